// Round 7
// baseline (654.417 us; speedup 1.0000x reference)
//
#include <hip/hip_runtime.h>

#define N_NODES 100000
#define HID 64
#define N_EDGES 1600000
#define NHB 256                // histogram blocks in prep
#define GATHER_BLOCKS 6250     // N_NODES*16/256 gather blocks in fused prep kernel
#define SCAN_NPT 98            // 1024 threads x 98 = 100352 >= N_NODES

typedef __attribute__((ext_vector_type(8))) short bf16x8;
typedef __attribute__((ext_vector_type(4))) float f32x4;

// ---- bf16 helpers (manual, RNE) ------------------------------------------
__device__ __forceinline__ unsigned short f2bf(float f) {
    unsigned u = __float_as_uint(f);
    u = (u + 0x7FFFu + ((u >> 16) & 1u)) >> 16;
    return (unsigned short)u;
}
__device__ __forceinline__ float bflo(unsigned w) { return __uint_as_float(w << 16); }
__device__ __forceinline__ float bfhi(unsigned w) { return __uint_as_float(w & 0xFFFF0000u); }

// ------------------------------------------------- fused gather->bf16 + degree hist
// Blocks [0, GATHER_BLOCKS): xh = bf16(emb[node_id]).
// Blocks [GATHER_BLOCKS, +NHB): node-level degree histogram via GLOBAL atomics
// into deg[] (400KB, L2-resident; ~16 increments/node spread over time, and
// same-address adds coalesce per-wave). Replaces the bucket-level LDS hist.
__global__ void prep_kernel(const float* __restrict__ emb,
                            const int* __restrict__ nid,
                            unsigned short* __restrict__ xh,
                            const int* __restrict__ dst,
                            int* __restrict__ deg) {
    if (blockIdx.x < GATHER_BLOCKS) {
        int i = blockIdx.x * blockDim.x + threadIdx.x;
        const int total = N_NODES * (HID / 4);
        if (i >= total) return;
        int row = i >> 4;
        int c   = i & 15;
        int s   = nid[row];
        float4 v = reinterpret_cast<const float4*>(emb)[(size_t)s * 16 + c];
        uint2 p;
        p.x = (unsigned)f2bf(v.x) | ((unsigned)f2bf(v.y) << 16);
        p.y = (unsigned)f2bf(v.z) | ((unsigned)f2bf(v.w) << 16);
        reinterpret_cast<uint2*>(xh)[(size_t)row * 16 + c] = p;
        return;
    }
    int hb = blockIdx.x - GATHER_BLOCKS;
    const int nt = NHB * 256;
    const int4* d4 = (const int4*)dst;
    for (int q = hb * blockDim.x + threadIdx.x; q < N_EDGES / 4; q += nt) {
        int4 v = d4[q];
        atomicAdd(&deg[v.x], 1);
        atomicAdd(&deg[v.y], 1);
        atomicAdd(&deg[v.z], 1);
        atomicAdd(&deg[v.w], 1);
    }
}

// ---------------------------------------------------------------- degree scan
// Single block, 1024 threads, SCAN_NPT contiguous elements/thread, two passes
// (sum then write-prefix) so no per-thread array. Writes row_start AND cursor.
__global__ void scan_kernel(const int* __restrict__ deg,
                            int* __restrict__ row_start,
                            int* __restrict__ cursor) {
    __shared__ int part[1024];
    int t = threadIdx.x;
    int i0 = t * SCAN_NPT;
    int i1 = i0 + SCAN_NPT; if (i1 > N_NODES) i1 = N_NODES;
    int s = 0;
    for (int i = i0; i < i1; ++i) s += deg[i];
    part[t] = s;
    __syncthreads();
    for (int off = 1; off < 1024; off <<= 1) {
        int u = (t >= off) ? part[t - off] : 0;
        __syncthreads();
        part[t] += u;
        __syncthreads();
    }
    int running = part[t] - s;     // exclusive prefix of this thread's chunk
    for (int i = i0; i < i1; ++i) {
        row_start[i] = running;
        cursor[i]    = running;
        running += deg[i];
    }
    if (t == 0) row_start[N_NODES] = N_EDGES;
}

// ---------------------------------------------------------------- direct scatter
// adj[atomicAdd(&cursor[dst],1)] = src. 1.6M atomics on the L2-resident 400KB
// cursor array + scattered 4B writes into the L2-fitting 6.4MB adj. Replaces
// bucket_scatter + bucket_csr (two kernels, 25MB pairs round-trip, two
// per-edge LDS-atomic passes). Within-row order becomes arbitrary -- the mean
// aggregation is order-independent.
__global__ void scatter_kernel(const int* __restrict__ src,
                               const int* __restrict__ dst,
                               int* __restrict__ cursor,
                               int* __restrict__ adj) {
    int q = blockIdx.x * blockDim.x + threadIdx.x;
    if (q >= N_EDGES / 4) return;
    int4 s = reinterpret_cast<const int4*>(src)[q];
    int4 d = reinterpret_cast<const int4*>(dst)[q];
    adj[atomicAdd(&cursor[d.x], 1)] = s.x;
    adj[atomicAdd(&cursor[d.y], 1)] = s.y;
    adj[atomicAdd(&cursor[d.z], 1)] = s.z;
    adj[atomicAdd(&cursor[d.w], 1)] = s.w;
}

// ---------------------------------------------------------------- aggregation
// (R4 form, measured as part of the 279us baseline.)
// 8 rows per wave x 8 lanes per row, uint4 (16B) gathers: 8 loads in flight
// = 128B/lane. Lane c owns features 8c..8c+7; the 8 consecutive rows of a
// wave write 1KB contiguous. No shuffle reduction.
__global__ void agg_kernel(const int* __restrict__ row_start,
                           const int* __restrict__ adj,
                           const unsigned short* __restrict__ xh,
                           unsigned short* __restrict__ M) {
    int lane = threadIdx.x & 63;
    int g = lane >> 3;                  // row group 0..7
    int c = lane & 7;                   // uint4 column (features 8c..8c+7)
    int wpb = blockDim.x >> 6;
    int wid = blockIdx.x * wpb + (threadIdx.x >> 6);
    int stride = gridDim.x * wpb;
    const uint4* xw = (const uint4*)xh;   // row stride = 8 uint4
    uint4* Mw = (uint4*)M;
    const int NQ = N_NODES / 8;           // 12500, exact
    for (int q = wid; q < NQ; q += stride) {
        int row = q * 8 + g;
        int beg = row_start[row], end = row_start[row + 1];
        float a0 = 0.f, a1 = 0.f, a2 = 0.f, a3 = 0.f;
        float a4 = 0.f, a5 = 0.f, a6 = 0.f, a7 = 0.f;
        int j = beg;
        for (; j + 7 < end; j += 8) {     // 8 uint4 gathers in flight
            int s0 = adj[j],     s1 = adj[j + 1], s2 = adj[j + 2], s3 = adj[j + 3];
            int s4 = adj[j + 4], s5 = adj[j + 5], s6 = adj[j + 6], s7 = adj[j + 7];
            uint4 v0 = xw[(size_t)s0 * 8 + c];
            uint4 v1 = xw[(size_t)s1 * 8 + c];
            uint4 v2 = xw[(size_t)s2 * 8 + c];
            uint4 v3 = xw[(size_t)s3 * 8 + c];
            uint4 v4 = xw[(size_t)s4 * 8 + c];
            uint4 v5 = xw[(size_t)s5 * 8 + c];
            uint4 v6 = xw[(size_t)s6 * 8 + c];
            uint4 v7 = xw[(size_t)s7 * 8 + c];
            a0 += bflo(v0.x) + bflo(v1.x) + bflo(v2.x) + bflo(v3.x)
                + bflo(v4.x) + bflo(v5.x) + bflo(v6.x) + bflo(v7.x);
            a1 += bfhi(v0.x) + bfhi(v1.x) + bfhi(v2.x) + bfhi(v3.x)
                + bfhi(v4.x) + bfhi(v5.x) + bfhi(v6.x) + bfhi(v7.x);
            a2 += bflo(v0.y) + bflo(v1.y) + bflo(v2.y) + bflo(v3.y)
                + bflo(v4.y) + bflo(v5.y) + bflo(v6.y) + bflo(v7.y);
            a3 += bfhi(v0.y) + bfhi(v1.y) + bfhi(v2.y) + bfhi(v3.y)
                + bfhi(v4.y) + bfhi(v5.y) + bfhi(v6.y) + bfhi(v7.y);
            a4 += bflo(v0.z) + bflo(v1.z) + bflo(v2.z) + bflo(v3.z)
                + bflo(v4.z) + bflo(v5.z) + bflo(v6.z) + bflo(v7.z);
            a5 += bfhi(v0.z) + bfhi(v1.z) + bfhi(v2.z) + bfhi(v3.z)
                + bfhi(v4.z) + bfhi(v5.z) + bfhi(v6.z) + bfhi(v7.z);
            a6 += bflo(v0.w) + bflo(v1.w) + bflo(v2.w) + bflo(v3.w)
                + bflo(v4.w) + bflo(v5.w) + bflo(v6.w) + bflo(v7.w);
            a7 += bfhi(v0.w) + bfhi(v1.w) + bfhi(v2.w) + bfhi(v3.w)
                + bfhi(v4.w) + bfhi(v5.w) + bfhi(v6.w) + bfhi(v7.w);
        }
        if (j + 3 < end) {                // 4 in flight
            int s0 = adj[j], s1 = adj[j + 1], s2 = adj[j + 2], s3 = adj[j + 3];
            uint4 v0 = xw[(size_t)s0 * 8 + c];
            uint4 v1 = xw[(size_t)s1 * 8 + c];
            uint4 v2 = xw[(size_t)s2 * 8 + c];
            uint4 v3 = xw[(size_t)s3 * 8 + c];
            a0 += bflo(v0.x) + bflo(v1.x) + bflo(v2.x) + bflo(v3.x);
            a1 += bfhi(v0.x) + bfhi(v1.x) + bfhi(v2.x) + bfhi(v3.x);
            a2 += bflo(v0.y) + bflo(v1.y) + bflo(v2.y) + bflo(v3.y);
            a3 += bfhi(v0.y) + bfhi(v1.y) + bfhi(v2.y) + bfhi(v3.y);
            a4 += bflo(v0.z) + bflo(v1.z) + bflo(v2.z) + bflo(v3.z);
            a5 += bfhi(v0.z) + bfhi(v1.z) + bfhi(v2.z) + bfhi(v3.z);
            a6 += bflo(v0.w) + bflo(v1.w) + bflo(v2.w) + bflo(v3.w);
            a7 += bfhi(v0.w) + bfhi(v1.w) + bfhi(v2.w) + bfhi(v3.w);
            j += 4;
        }
        for (; j < end; ++j) {
            uint4 v = xw[(size_t)adj[j] * 8 + c];
            a0 += bflo(v.x); a1 += bfhi(v.x);
            a2 += bflo(v.y); a3 += bfhi(v.y);
            a4 += bflo(v.z); a5 += bfhi(v.z);
            a6 += bflo(v.w); a7 += bfhi(v.w);
        }
        float inv = 1.0f / fmaxf((float)(end - beg), 1.0f);
        uint4 p;
        p.x = (unsigned)f2bf(a0 * inv) | ((unsigned)f2bf(a1 * inv) << 16);
        p.y = (unsigned)f2bf(a2 * inv) | ((unsigned)f2bf(a3 * inv) << 16);
        p.z = (unsigned)f2bf(a4 * inv) | ((unsigned)f2bf(a5 * inv) << 16);
        p.w = (unsigned)f2bf(a6 * inv) | ((unsigned)f2bf(a7 * inv) << 16);
        Mw[(size_t)row * 8 + c] = p;      // 8 rows/wave -> 1KB contiguous
    }
}

// ---------------------------------------------------------------- MFMA GEMM
__global__ void gemm_kernel(const unsigned short* __restrict__ Am,
                            const unsigned short* __restrict__ As,
                            const float* __restrict__ Wl,
                            const float* __restrict__ Wr,
                            const float* __restrict__ bias,
                            unsigned short* __restrict__ H,
                            int relu) {
    int lane = threadIdx.x & 63;
    int m = lane & 15, quad = lane >> 4;

    bf16x8 wf[2][2][4];   // [matrix][kstep][ctile]
    for (int mat = 0; mat < 2; ++mat) {
        const float* W = mat ? Wr : Wl;
        for (int ks = 0; ks < 2; ++ks)
            for (int ct = 0; ct < 4; ++ct) {
                const float* p = W + (ct * 16 + m) * HID + ks * 32 + quad * 8;
                bf16x8 f;
                #pragma unroll
                for (int j = 0; j < 8; ++j) f[j] = (short)f2bf(p[j]);
                wf[mat][ks][ct] = f;
            }
    }
    float bv[4];
    #pragma unroll
    for (int ct = 0; ct < 4; ++ct) bv[ct] = bias[ct * 16 + m];

    int wpb = blockDim.x >> 6;
    int wid = blockIdx.x * wpb + (threadIdx.x >> 6);
    int stride = gridDim.x * wpb;
    const int NT = N_NODES / 16;
    for (int t = wid; t < NT; t += stride) {
        f32x4 acc[4] = {{0,0,0,0},{0,0,0,0},{0,0,0,0},{0,0,0,0}};
        size_t rowbase = ((size_t)t * 16 + m) * HID;
        #pragma unroll
        for (int ks = 0; ks < 2; ++ks) {
            bf16x8 a0 = *(const bf16x8*)(Am + rowbase + ks * 32 + quad * 8);
            bf16x8 a1 = *(const bf16x8*)(As + rowbase + ks * 32 + quad * 8);
            #pragma unroll
            for (int ct = 0; ct < 4; ++ct) {
                acc[ct] = __builtin_amdgcn_mfma_f32_16x16x32_bf16(a0, wf[0][ks][ct], acc[ct], 0, 0, 0);
                acc[ct] = __builtin_amdgcn_mfma_f32_16x16x32_bf16(a1, wf[1][ks][ct], acc[ct], 0, 0, 0);
            }
        }
        #pragma unroll
        for (int ct = 0; ct < 4; ++ct) {
            #pragma unroll
            for (int r = 0; r < 4; ++r) {
                float v = acc[ct][r] + bv[ct];
                if (relu) v = fmaxf(v, 0.f);
                H[((size_t)t * 16 + quad * 4 + r) * HID + ct * 16 + m] = f2bf(v);
            }
        }
    }
}

// ---------------------------------------------------------------- edge dot (bf16)
// Flat edge-order form (measured 43.1us at the 3.64 TB/s fetch-path ceiling):
// 8 lanes per 2 consecutive edges, 4 uint4 gathers in flight/lane,
// coalesced float2 output write. No per-row loop -> MLP never collapses.
__global__ void edge_dot_kernel(const int* __restrict__ src,
                                const int* __restrict__ dst,
                                const unsigned short* __restrict__ h,
                                float* __restrict__ out) {
    int t = blockIdx.x * blockDim.x + threadIdx.x;
    int g = t >> 3;                 // edge-pair group
    int c = t & 7;
    int e0 = g * 2;
    if (e0 >= N_EDGES) return;
    int a0 = src[e0],     b0 = dst[e0];
    int a1 = src[e0 + 1], b1 = dst[e0 + 1];
    const uint4* h4 = reinterpret_cast<const uint4*>(h);
    uint4 va0 = h4[(size_t)a0 * 8 + c];
    uint4 vb0 = h4[(size_t)b0 * 8 + c];
    uint4 va1 = h4[(size_t)a1 * 8 + c];
    uint4 vb1 = h4[(size_t)b1 * 8 + c];
    float p0 = bflo(va0.x) * bflo(vb0.x) + bfhi(va0.x) * bfhi(vb0.x)
             + bflo(va0.y) * bflo(vb0.y) + bfhi(va0.y) * bfhi(vb0.y)
             + bflo(va0.z) * bflo(vb0.z) + bfhi(va0.z) * bfhi(vb0.z)
             + bflo(va0.w) * bflo(vb0.w) + bfhi(va0.w) * bfhi(vb0.w);
    float p1 = bflo(va1.x) * bflo(vb1.x) + bfhi(va1.x) * bfhi(vb1.x)
             + bflo(va1.y) * bflo(vb1.y) + bfhi(va1.y) * bfhi(vb1.y)
             + bflo(va1.z) * bflo(vb1.z) + bfhi(va1.z) * bfhi(vb1.z)
             + bflo(va1.w) * bflo(vb1.w) + bfhi(va1.w) * bfhi(vb1.w);
    p0 += __shfl_xor(p0, 1); p0 += __shfl_xor(p0, 2); p0 += __shfl_xor(p0, 4);
    p1 += __shfl_xor(p1, 1); p1 += __shfl_xor(p1, 2); p1 += __shfl_xor(p1, 4);
    if (c == 0) reinterpret_cast<float2*>(out)[g] = make_float2(p0, p1);
}

extern "C" void kernel_launch(void* const* d_in, const int* in_sizes, int n_in,
                              void* d_out, int out_size, void* d_ws, size_t ws_size,
                              hipStream_t stream) {
    const float* emb = (const float*)d_in[0];
    const float* Wl1 = (const float*)d_in[1];
    const float* Wr1 = (const float*)d_in[2];
    const float* b1  = (const float*)d_in[3];
    const float* Wl2 = (const float*)d_in[4];
    const float* Wr2 = (const float*)d_in[5];
    const float* b2  = (const float*)d_in[6];
    const int*   nid = (const int*)d_in[7];
    const int*   ei  = (const int*)d_in[8];
    const int* esrc = ei;
    const int* edst = ei + N_EDGES;
    float* out = (float*)d_out;

    const size_t NH = (size_t)N_NODES * HID;   // 6.4M elements
    unsigned short* xh  = (unsigned short*)d_ws;          // [N,64] bf16
    unsigned short* h1h = xh + NH;                        // [N,64] bf16
    unsigned short* h2h = h1h + NH;                       // [N,64] bf16
    unsigned short* M   = h2h + NH;                       // [N,64] bf16 (mean agg)
    int* ib        = (int*)(M + NH);                      // int region
    int* row_start = ib;                          // [N+1]
    int* adj       = ib + N_NODES + 64;           // [E]
    int* deg       = adj + N_EDGES + 64;          // [N]
    int* cursor    = deg + N_NODES;               // [N]

    hipMemsetAsync(deg, 0, N_NODES * sizeof(int), stream);

    // fused: xh = bf16(emb[node_id])  +  node-degree histogram (global atomics)
    prep_kernel<<<GATHER_BLOCKS + NHB, 256, 0, stream>>>(emb, nid, xh, edst, deg);

    // ---- CSR build: scan degrees, then direct atomic scatter
    scan_kernel<<<1, 1024, 0, stream>>>(deg, row_start, cursor);
    scatter_kernel<<<(N_EDGES / 4 + 255) / 256, 256, 0, stream>>>(esrc, edst, cursor, adj);

    // ---- layer 1: aggregate then MFMA GEMM (+relu)
    agg_kernel<<<2048, 256, 0, stream>>>(row_start, adj, xh, M);
    gemm_kernel<<<512, 256, 0, stream>>>(M, xh, Wl1, Wr1, b1, h1h, 1);

    // ---- layer 2
    agg_kernel<<<2048, 256, 0, stream>>>(row_start, adj, h1h, M);
    gemm_kernel<<<512, 256, 0, stream>>>(M, h1h, Wl2, Wr2, b2, h2h, 0);

    // ---- edge classifier on bf16 features (flat edge-order, at path ceiling)
    edge_dot_kernel<<<((size_t)(N_EDGES / 2) * 8 + 255) / 256, 256, 0, stream>>>(esrc, edst, h2h, out);
}

// Round 8
// 278.448 us; speedup vs baseline: 2.3502x; 2.3502x over previous
//
#include <hip/hip_runtime.h>

#define N_NODES 100000
#define HID 64
#define N_EDGES 1600000
#define NB 391                 // ceil(N_NODES / 256) buckets of 256 nodes
#define NBP 392                // padded hist row (partial-hist stride)
#define NHB 256                // histogram blocks
#define C_EPB 6400             // edges per block in bucket_scatter (250 blocks)
#define GATHER_BLOCKS 6250     // N_NODES*16/256 gather blocks in fused prep kernel

typedef __attribute__((ext_vector_type(8))) short bf16x8;
typedef __attribute__((ext_vector_type(4))) float f32x4;

// ---- bf16 helpers (manual, RNE) ------------------------------------------
__device__ __forceinline__ unsigned short f2bf(float f) {
    unsigned u = __float_as_uint(f);
    u = (u + 0x7FFFu + ((u >> 16) & 1u)) >> 16;
    return (unsigned short)u;
}
__device__ __forceinline__ float bflo(unsigned w) { return __uint_as_float(w << 16); }
__device__ __forceinline__ float bfhi(unsigned w) { return __uint_as_float(w & 0xFFFF0000u); }

// ------------------------------------------------- fused gather->bf16 + hist
// Blocks [0, GATHER_BLOCKS): xh = bf16(emb[node_id]).
// Blocks [GATHER_BLOCKS, +NHB): per-block PARTIAL dst-bucket histograms
// (LDS atomics only), written non-atomically to bhist_part (reduced in
// bucket_scan). NO device-scope per-edge atomics anywhere (R7 lesson: 1.6M
// device atomics cost ~100us+ on this 8-XCD part).
__global__ void gather_hist_kernel(const float* __restrict__ emb,
                                   const int* __restrict__ nid,
                                   unsigned short* __restrict__ xh,
                                   const int* __restrict__ dst,
                                   int* __restrict__ bhist_part) {
    if (blockIdx.x < GATHER_BLOCKS) {
        int i = blockIdx.x * blockDim.x + threadIdx.x;
        const int total = N_NODES * (HID / 4);
        if (i >= total) return;
        int row = i >> 4;
        int c   = i & 15;
        int s   = nid[row];
        float4 v = reinterpret_cast<const float4*>(emb)[(size_t)s * 16 + c];
        uint2 p;
        p.x = (unsigned)f2bf(v.x) | ((unsigned)f2bf(v.y) << 16);
        p.y = (unsigned)f2bf(v.z) | ((unsigned)f2bf(v.w) << 16);
        reinterpret_cast<uint2*>(xh)[(size_t)row * 16 + c] = p;
        return;
    }
    // ---- histogram part (NHB blocks)
    __shared__ int h[NB];
    for (int i = threadIdx.x; i < NB; i += blockDim.x) h[i] = 0;
    __syncthreads();
    int hb = blockIdx.x - GATHER_BLOCKS;
    const int nt = NHB * 256;
    const int4* d4 = (const int4*)dst;
    for (int q = hb * blockDim.x + threadIdx.x; q < N_EDGES / 4; q += nt) {
        int4 v = d4[q];
        atomicAdd(&h[v.x >> 8], 1);
        atomicAdd(&h[v.y >> 8], 1);
        atomicAdd(&h[v.z >> 8], 1);
        atomicAdd(&h[v.w >> 8], 1);
    }
    __syncthreads();
    for (int i = threadIdx.x; i < NB; i += blockDim.x)
        bhist_part[hb * NBP + i] = h[i];
}

// ---------------------------------------------------------------- CSR build, pass B
// Reduce the NHB partial histograms, then exclusive-scan over 391 buckets.
// (391 elements, one block -- NOT the 100K-element single-block scan that
// cost 229us in R7.)
__global__ void bucket_scan(const int* __restrict__ bhist_part,
                            int* __restrict__ boff,
                            int* __restrict__ bcursor) {
    __shared__ int s[512];
    int v = 0;
    if (threadIdx.x < NB) {
        #pragma unroll 8
        for (int p = 0; p < NHB; ++p) v += bhist_part[p * NBP + threadIdx.x];
    }
    s[threadIdx.x] = v;
    __syncthreads();
    for (int off = 1; off < 512; off <<= 1) {
        int t = (threadIdx.x >= off) ? s[threadIdx.x - off] : 0;
        __syncthreads();
        s[threadIdx.x] += t;
        __syncthreads();
    }
    if (threadIdx.x < NB) {
        int ex = s[threadIdx.x] - v;
        boff[threadIdx.x] = ex;
        bcursor[threadIdx.x] = ex;
    }
}

// ---------------------------------------------------------------- CSR build, pass C
// PACKED pairs: one int = (src << 8) | (dst & 255). src < 2^17 so it fits.
// Halves the scatter write (12.8->6.4 MB) and the csr read (25.6->12.8 MB)
// vs the old int2 form. Global atomics only per (block,bucket): ~98K total.
__global__ void bucket_scatter(const int* __restrict__ src,
                               const int* __restrict__ dst,
                               int* __restrict__ bcursor,
                               int* __restrict__ pairs) {
    __shared__ int h[NB];
    __shared__ int base[NB];
    for (int i = threadIdx.x; i < NB; i += blockDim.x) h[i] = 0;
    __syncthreads();
    int e0 = blockIdx.x * C_EPB;
    int e1 = e0 + C_EPB; if (e1 > N_EDGES) e1 = N_EDGES;
    for (int e = e0 + threadIdx.x; e < e1; e += blockDim.x)
        atomicAdd(&h[dst[e] >> 8], 1);
    __syncthreads();
    for (int i = threadIdx.x; i < NB; i += blockDim.x) {
        int c = h[i];
        base[i] = c ? atomicAdd(&bcursor[i], c) : 0;
    }
    __syncthreads();
    for (int i = threadIdx.x; i < NB; i += blockDim.x) h[i] = 0;
    __syncthreads();
    for (int e = e0 + threadIdx.x; e < e1; e += blockDim.x) {
        int d = dst[e];
        int b = d >> 8;
        int slot = base[b] + atomicAdd(&h[b], 1);
        pairs[slot] = (src[e] << 8) | (d & 255);
    }
}

// ---------------------------------------------------------------- CSR build, pass D
__global__ void bucket_csr(const int* __restrict__ pairs,
                           const int* __restrict__ boff,
                           const int* __restrict__ bcursor,
                           int* __restrict__ row_start,
                           int* __restrict__ adj) {
    __shared__ int cnt[256];
    __shared__ int sc[256];
    int b = blockIdx.x;
    int node0 = b << 8;
    int p0 = boff[b];
    int p1 = bcursor[b];           // after pass C, bcursor[b] = end of bucket b
    int t = threadIdx.x;
    cnt[t] = 0;
    __syncthreads();
    for (int p = p0 + t; p < p1; p += 256)
        atomicAdd(&cnt[pairs[p] & 255], 1);
    __syncthreads();
    int v = cnt[t];
    sc[t] = v;
    __syncthreads();
    for (int off = 1; off < 256; off <<= 1) {
        int u = (t >= off) ? sc[t - off] : 0;
        __syncthreads();
        sc[t] += u;
        __syncthreads();
    }
    sc[t] = p0 + sc[t] - v;        // exclusive scan + bucket base = row_start
    __syncthreads();
    int node = node0 + t;
    if (node <= N_NODES) row_start[node] = sc[t];
    __syncthreads();               // row_start read before atomics mutate sc
    for (int p = p0 + t; p < p1; p += 256) {
        int pr = pairs[p];
        int slot = atomicAdd(&sc[pr & 255], 1);
        adj[slot] = (int)(((unsigned)pr) >> 8);
    }
}

// ---------------------------------------------------------------- aggregation
// (R4 form, part of the measured 279us baseline.)
// 8 rows per wave x 8 lanes per row, uint4 (16B) gathers: 8 loads in flight
// = 128B/lane. Lane c owns features 8c..8c+7; the 8 consecutive rows of a
// wave write 1KB contiguous. No shuffle reduction.
__global__ void agg_kernel(const int* __restrict__ row_start,
                           const int* __restrict__ adj,
                           const unsigned short* __restrict__ xh,
                           unsigned short* __restrict__ M) {
    int lane = threadIdx.x & 63;
    int g = lane >> 3;                  // row group 0..7
    int c = lane & 7;                   // uint4 column (features 8c..8c+7)
    int wpb = blockDim.x >> 6;
    int wid = blockIdx.x * wpb + (threadIdx.x >> 6);
    int stride = gridDim.x * wpb;
    const uint4* xw = (const uint4*)xh;   // row stride = 8 uint4
    uint4* Mw = (uint4*)M;
    const int NQ = N_NODES / 8;           // 12500, exact
    for (int q = wid; q < NQ; q += stride) {
        int row = q * 8 + g;
        int beg = row_start[row], end = row_start[row + 1];
        float a0 = 0.f, a1 = 0.f, a2 = 0.f, a3 = 0.f;
        float a4 = 0.f, a5 = 0.f, a6 = 0.f, a7 = 0.f;
        int j = beg;
        for (; j + 7 < end; j += 8) {     // 8 uint4 gathers in flight
            int s0 = adj[j],     s1 = adj[j + 1], s2 = adj[j + 2], s3 = adj[j + 3];
            int s4 = adj[j + 4], s5 = adj[j + 5], s6 = adj[j + 6], s7 = adj[j + 7];
            uint4 v0 = xw[(size_t)s0 * 8 + c];
            uint4 v1 = xw[(size_t)s1 * 8 + c];
            uint4 v2 = xw[(size_t)s2 * 8 + c];
            uint4 v3 = xw[(size_t)s3 * 8 + c];
            uint4 v4 = xw[(size_t)s4 * 8 + c];
            uint4 v5 = xw[(size_t)s5 * 8 + c];
            uint4 v6 = xw[(size_t)s6 * 8 + c];
            uint4 v7 = xw[(size_t)s7 * 8 + c];
            a0 += bflo(v0.x) + bflo(v1.x) + bflo(v2.x) + bflo(v3.x)
                + bflo(v4.x) + bflo(v5.x) + bflo(v6.x) + bflo(v7.x);
            a1 += bfhi(v0.x) + bfhi(v1.x) + bfhi(v2.x) + bfhi(v3.x)
                + bfhi(v4.x) + bfhi(v5.x) + bfhi(v6.x) + bfhi(v7.x);
            a2 += bflo(v0.y) + bflo(v1.y) + bflo(v2.y) + bflo(v3.y)
                + bflo(v4.y) + bflo(v5.y) + bflo(v6.y) + bflo(v7.y);
            a3 += bfhi(v0.y) + bfhi(v1.y) + bfhi(v2.y) + bfhi(v3.y)
                + bfhi(v4.y) + bfhi(v5.y) + bfhi(v6.y) + bfhi(v7.y);
            a4 += bflo(v0.z) + bflo(v1.z) + bflo(v2.z) + bflo(v3.z)
                + bflo(v4.z) + bflo(v5.z) + bflo(v6.z) + bflo(v7.z);
            a5 += bfhi(v0.z) + bfhi(v1.z) + bfhi(v2.z) + bfhi(v3.z)
                + bfhi(v4.z) + bfhi(v5.z) + bfhi(v6.z) + bfhi(v7.z);
            a6 += bflo(v0.w) + bflo(v1.w) + bflo(v2.w) + bflo(v3.w)
                + bflo(v4.w) + bflo(v5.w) + bflo(v6.w) + bflo(v7.w);
            a7 += bfhi(v0.w) + bfhi(v1.w) + bfhi(v2.w) + bfhi(v3.w)
                + bfhi(v4.w) + bfhi(v5.w) + bfhi(v6.w) + bfhi(v7.w);
        }
        if (j + 3 < end) {                // 4 in flight
            int s0 = adj[j], s1 = adj[j + 1], s2 = adj[j + 2], s3 = adj[j + 3];
            uint4 v0 = xw[(size_t)s0 * 8 + c];
            uint4 v1 = xw[(size_t)s1 * 8 + c];
            uint4 v2 = xw[(size_t)s2 * 8 + c];
            uint4 v3 = xw[(size_t)s3 * 8 + c];
            a0 += bflo(v0.x) + bflo(v1.x) + bflo(v2.x) + bflo(v3.x);
            a1 += bfhi(v0.x) + bfhi(v1.x) + bfhi(v2.x) + bfhi(v3.x);
            a2 += bflo(v0.y) + bflo(v1.y) + bflo(v2.y) + bflo(v3.y);
            a3 += bfhi(v0.y) + bfhi(v1.y) + bfhi(v2.y) + bfhi(v3.y);
            a4 += bflo(v0.z) + bflo(v1.z) + bflo(v2.z) + bflo(v3.z);
            a5 += bfhi(v0.z) + bfhi(v1.z) + bfhi(v2.z) + bfhi(v3.z);
            a6 += bflo(v0.w) + bflo(v1.w) + bflo(v2.w) + bflo(v3.w);
            a7 += bfhi(v0.w) + bfhi(v1.w) + bfhi(v2.w) + bfhi(v3.w);
            j += 4;
        }
        for (; j < end; ++j) {
            uint4 v = xw[(size_t)adj[j] * 8 + c];
            a0 += bflo(v.x); a1 += bfhi(v.x);
            a2 += bflo(v.y); a3 += bfhi(v.y);
            a4 += bflo(v.z); a5 += bfhi(v.z);
            a6 += bflo(v.w); a7 += bfhi(v.w);
        }
        float inv = 1.0f / fmaxf((float)(end - beg), 1.0f);
        uint4 p;
        p.x = (unsigned)f2bf(a0 * inv) | ((unsigned)f2bf(a1 * inv) << 16);
        p.y = (unsigned)f2bf(a2 * inv) | ((unsigned)f2bf(a3 * inv) << 16);
        p.z = (unsigned)f2bf(a4 * inv) | ((unsigned)f2bf(a5 * inv) << 16);
        p.w = (unsigned)f2bf(a6 * inv) | ((unsigned)f2bf(a7 * inv) << 16);
        Mw[(size_t)row * 8 + c] = p;      // 8 rows/wave -> 1KB contiguous
    }
}

// ---------------------------------------------------------------- MFMA GEMM
__global__ void gemm_kernel(const unsigned short* __restrict__ Am,
                            const unsigned short* __restrict__ As,
                            const float* __restrict__ Wl,
                            const float* __restrict__ Wr,
                            const float* __restrict__ bias,
                            unsigned short* __restrict__ H,
                            int relu) {
    int lane = threadIdx.x & 63;
    int m = lane & 15, quad = lane >> 4;

    bf16x8 wf[2][2][4];   // [matrix][kstep][ctile]
    for (int mat = 0; mat < 2; ++mat) {
        const float* W = mat ? Wr : Wl;
        for (int ks = 0; ks < 2; ++ks)
            for (int ct = 0; ct < 4; ++ct) {
                const float* p = W + (ct * 16 + m) * HID + ks * 32 + quad * 8;
                bf16x8 f;
                #pragma unroll
                for (int j = 0; j < 8; ++j) f[j] = (short)f2bf(p[j]);
                wf[mat][ks][ct] = f;
            }
    }
    float bv[4];
    #pragma unroll
    for (int ct = 0; ct < 4; ++ct) bv[ct] = bias[ct * 16 + m];

    int wpb = blockDim.x >> 6;
    int wid = blockIdx.x * wpb + (threadIdx.x >> 6);
    int stride = gridDim.x * wpb;
    const int NT = N_NODES / 16;
    for (int t = wid; t < NT; t += stride) {
        f32x4 acc[4] = {{0,0,0,0},{0,0,0,0},{0,0,0,0},{0,0,0,0}};
        size_t rowbase = ((size_t)t * 16 + m) * HID;
        #pragma unroll
        for (int ks = 0; ks < 2; ++ks) {
            bf16x8 a0 = *(const bf16x8*)(Am + rowbase + ks * 32 + quad * 8);
            bf16x8 a1 = *(const bf16x8*)(As + rowbase + ks * 32 + quad * 8);
            #pragma unroll
            for (int ct = 0; ct < 4; ++ct) {
                acc[ct] = __builtin_amdgcn_mfma_f32_16x16x32_bf16(a0, wf[0][ks][ct], acc[ct], 0, 0, 0);
                acc[ct] = __builtin_amdgcn_mfma_f32_16x16x32_bf16(a1, wf[1][ks][ct], acc[ct], 0, 0, 0);
            }
        }
        #pragma unroll
        for (int ct = 0; ct < 4; ++ct) {
            #pragma unroll
            for (int r = 0; r < 4; ++r) {
                float v = acc[ct][r] + bv[ct];
                if (relu) v = fmaxf(v, 0.f);
                H[((size_t)t * 16 + quad * 4 + r) * HID + ct * 16 + m] = f2bf(v);
            }
        }
    }
}

// ---------------------------------------------------------------- edge dot (bf16)
// Flat edge-order form (measured 43.1us at the 3.64 TB/s fetch-path ceiling):
// 8 lanes per 2 consecutive edges, 4 uint4 gathers in flight/lane,
// coalesced float2 output write. No per-row loop -> MLP never collapses.
__global__ void edge_dot_kernel(const int* __restrict__ src,
                                const int* __restrict__ dst,
                                const unsigned short* __restrict__ h,
                                float* __restrict__ out) {
    int t = blockIdx.x * blockDim.x + threadIdx.x;
    int g = t >> 3;                 // edge-pair group
    int c = t & 7;
    int e0 = g * 2;
    if (e0 >= N_EDGES) return;
    int a0 = src[e0],     b0 = dst[e0];
    int a1 = src[e0 + 1], b1 = dst[e0 + 1];
    const uint4* h4 = reinterpret_cast<const uint4*>(h);
    uint4 va0 = h4[(size_t)a0 * 8 + c];
    uint4 vb0 = h4[(size_t)b0 * 8 + c];
    uint4 va1 = h4[(size_t)a1 * 8 + c];
    uint4 vb1 = h4[(size_t)b1 * 8 + c];
    float p0 = bflo(va0.x) * bflo(vb0.x) + bfhi(va0.x) * bfhi(vb0.x)
             + bflo(va0.y) * bflo(vb0.y) + bfhi(va0.y) * bfhi(vb0.y)
             + bflo(va0.z) * bflo(vb0.z) + bfhi(va0.z) * bfhi(vb0.z)
             + bflo(va0.w) * bflo(vb0.w) + bfhi(va0.w) * bfhi(vb0.w);
    float p1 = bflo(va1.x) * bflo(vb1.x) + bfhi(va1.x) * bfhi(vb1.x)
             + bflo(va1.y) * bflo(vb1.y) + bfhi(va1.y) * bfhi(vb1.y)
             + bflo(va1.z) * bflo(vb1.z) + bfhi(va1.z) * bfhi(vb1.z)
             + bflo(va1.w) * bflo(vb1.w) + bfhi(va1.w) * bfhi(vb1.w);
    p0 += __shfl_xor(p0, 1); p0 += __shfl_xor(p0, 2); p0 += __shfl_xor(p0, 4);
    p1 += __shfl_xor(p1, 1); p1 += __shfl_xor(p1, 2); p1 += __shfl_xor(p1, 4);
    if (c == 0) reinterpret_cast<float2*>(out)[g] = make_float2(p0, p1);
}

extern "C" void kernel_launch(void* const* d_in, const int* in_sizes, int n_in,
                              void* d_out, int out_size, void* d_ws, size_t ws_size,
                              hipStream_t stream) {
    const float* emb = (const float*)d_in[0];
    const float* Wl1 = (const float*)d_in[1];
    const float* Wr1 = (const float*)d_in[2];
    const float* b1  = (const float*)d_in[3];
    const float* Wl2 = (const float*)d_in[4];
    const float* Wr2 = (const float*)d_in[5];
    const float* b2  = (const float*)d_in[6];
    const int*   nid = (const int*)d_in[7];
    const int*   ei  = (const int*)d_in[8];
    const int* esrc = ei;
    const int* edst = ei + N_EDGES;
    float* out = (float*)d_out;

    const size_t NH = (size_t)N_NODES * HID;   // 6.4M elements
    unsigned short* xh  = (unsigned short*)d_ws;          // [N,64] bf16
    unsigned short* h1h = xh + NH;                        // [N,64] bf16
    unsigned short* h2h = h1h + NH;                       // [N,64] bf16
    unsigned short* M   = h2h + NH;                       // [N,64] bf16 (mean agg)
    int* ib        = (int*)(M + NH);                      // int region
    int* row_start = ib;                          // [N+1]
    int* adj       = ib + N_NODES + 64;           // [E]
    int* pairs     = adj + N_EDGES + 64;          // [E] packed (src<<8)|(dst&255)
    int* bhist_part = pairs + N_EDGES;            // [NHB*NBP] partial hists
    int* boff      = bhist_part + NHB * NBP;      // [NB]
    int* bcursor   = boff + NB + 1;               // [NB]

    // fused: xh = bf16(emb[node_id])  +  partial dst-bucket histograms
    gather_hist_kernel<<<GATHER_BLOCKS + NHB, 256, 0, stream>>>(emb, nid, xh, edst, bhist_part);

    // ---- CSR build via bucket counting sort (shared by both layers)
    bucket_scan<<<1, 512, 0, stream>>>(bhist_part, boff, bcursor);
    bucket_scatter<<<(N_EDGES + C_EPB - 1) / C_EPB, 256, 0, stream>>>(esrc, edst, bcursor, pairs);
    bucket_csr<<<NB, 256, 0, stream>>>(pairs, boff, bcursor, row_start, adj);

    // ---- layer 1: aggregate then MFMA GEMM (+relu)
    agg_kernel<<<2048, 256, 0, stream>>>(row_start, adj, xh, M);
    gemm_kernel<<<512, 256, 0, stream>>>(M, xh, Wl1, Wr1, b1, h1h, 1);

    // ---- layer 2
    agg_kernel<<<2048, 256, 0, stream>>>(row_start, adj, h1h, M);
    gemm_kernel<<<512, 256, 0, stream>>>(M, h1h, Wl2, Wr2, b2, h2h, 0);

    // ---- edge classifier on bf16 features (flat edge-order, at path ceiling)
    edge_dot_kernel<<<((size_t)(N_EDGES / 2) * 8 + 255) / 256, 256, 0, stream>>>(esrc, edst, h2h, out);
}

// Round 9
// 269.722 us; speedup vs baseline: 2.4263x; 1.0324x over previous
//
#include <hip/hip_runtime.h>

#define N_NODES 100000
#define HID 64
#define N_EDGES 1600000
#define NB 391                 // ceil(N_NODES / 256) buckets of 256 nodes
#define NBP 392                // padded hist row (partial-hist stride)
#define NHB 250                // hist chunks == scatter blocks (6400 edges each)
#define C_EPB 6400             // edges per block in bucket_scatter (250 blocks)
#define GATHER_BLOCKS 6250     // N_NODES*16/256 gather blocks in fused prep kernel

typedef __attribute__((ext_vector_type(8))) short bf16x8;
typedef __attribute__((ext_vector_type(4))) float f32x4;

// ---- bf16 helpers (manual, RNE) ------------------------------------------
__device__ __forceinline__ unsigned short f2bf(float f) {
    unsigned u = __float_as_uint(f);
    u = (u + 0x7FFFu + ((u >> 16) & 1u)) >> 16;
    return (unsigned short)u;
}
__device__ __forceinline__ float bflo(unsigned w) { return __uint_as_float(w << 16); }
__device__ __forceinline__ float bfhi(unsigned w) { return __uint_as_float(w & 0xFFFF0000u); }

// ------------------------------------------------- fused gather->bf16 + hist
// Blocks [0, GATHER_BLOCKS): xh = bf16(emb[node_id]).
// Blocks [GATHER_BLOCKS, +NHB): per-CHUNK dst-bucket histograms over the
// CONTIGUOUS edge range [hb*C_EPB, (hb+1)*C_EPB) -- the same range scatter
// block hb owns, so scatter can load its histogram instead of recomputing it.
// LDS atomics only; partials written non-atomically (R7 lesson: no per-edge
// device atomics).
__global__ void gather_hist_kernel(const float* __restrict__ emb,
                                   const int* __restrict__ nid,
                                   unsigned short* __restrict__ xh,
                                   const int* __restrict__ dst,
                                   int* __restrict__ bhist_part) {
    if (blockIdx.x < GATHER_BLOCKS) {
        int i = blockIdx.x * blockDim.x + threadIdx.x;
        const int total = N_NODES * (HID / 4);
        if (i >= total) return;
        int row = i >> 4;
        int c   = i & 15;
        int s   = nid[row];
        float4 v = reinterpret_cast<const float4*>(emb)[(size_t)s * 16 + c];
        uint2 p;
        p.x = (unsigned)f2bf(v.x) | ((unsigned)f2bf(v.y) << 16);
        p.y = (unsigned)f2bf(v.z) | ((unsigned)f2bf(v.w) << 16);
        reinterpret_cast<uint2*>(xh)[(size_t)row * 16 + c] = p;
        return;
    }
    // ---- histogram part (NHB blocks, contiguous chunks)
    __shared__ int h[NB];
    for (int i = threadIdx.x; i < NB; i += blockDim.x) h[i] = 0;
    __syncthreads();
    int hb = blockIdx.x - GATHER_BLOCKS;          // 0..NHB-1
    const int4* d4 = (const int4*)dst;
    int q0 = hb * (C_EPB / 4);
    int q1 = q0 + (C_EPB / 4);
    for (int q = q0 + threadIdx.x; q < q1; q += blockDim.x) {
        int4 v = d4[q];
        atomicAdd(&h[v.x >> 8], 1);
        atomicAdd(&h[v.y >> 8], 1);
        atomicAdd(&h[v.z >> 8], 1);
        atomicAdd(&h[v.w >> 8], 1);
    }
    __syncthreads();
    for (int i = threadIdx.x; i < NB; i += blockDim.x)
        bhist_part[hb * NBP + i] = h[i];
}

// ---------------------------------------------------------------- CSR build, pass B
// Reduce the NHB chunk histograms, then exclusive-scan over 391 buckets.
__global__ void bucket_scan(const int* __restrict__ bhist_part,
                            int* __restrict__ boff,
                            int* __restrict__ bcursor) {
    __shared__ int s[512];
    int v = 0;
    if (threadIdx.x < NB) {
        #pragma unroll 8
        for (int p = 0; p < NHB; ++p) v += bhist_part[p * NBP + threadIdx.x];
    }
    s[threadIdx.x] = v;
    __syncthreads();
    for (int off = 1; off < 512; off <<= 1) {
        int t = (threadIdx.x >= off) ? s[threadIdx.x - off] : 0;
        __syncthreads();
        s[threadIdx.x] += t;
        __syncthreads();
    }
    if (threadIdx.x < NB) {
        int ex = s[threadIdx.x] - v;
        boff[threadIdx.x] = ex;
        bcursor[threadIdx.x] = ex;
    }
}

// ---------------------------------------------------------------- CSR build, pass C
// ONE per-edge pass (was 3): per-block histogram comes precomputed from prep's
// chunk partials; 1024 threads (was 256) for 4x the latency hiding.
// pairs packs (src << 8) | (dst & 255). ~98K global atomics total (per
// block x bucket, not per edge).
__global__ void bucket_scatter(const int* __restrict__ src,
                               const int* __restrict__ dst,
                               const int* __restrict__ bhist_part,
                               int* __restrict__ bcursor,
                               int* __restrict__ pairs) {
    __shared__ int h[NB];
    __shared__ int base[NB];
    int blk = blockIdx.x;
    for (int i = threadIdx.x; i < NB; i += blockDim.x) {
        int c = bhist_part[blk * NBP + i];
        base[i] = c ? atomicAdd(&bcursor[i], c) : 0;
        h[i] = 0;
    }
    __syncthreads();
    int e0 = blk * C_EPB;
    int e1 = e0 + C_EPB;            // N_EDGES % C_EPB == 0, no tail
    for (int e = e0 + threadIdx.x; e < e1; e += blockDim.x) {
        int d = dst[e];
        int b = d >> 8;
        int slot = base[b] + atomicAdd(&h[b], 1);
        pairs[slot] = (src[e] << 8) | (d & 255);
    }
}

// ---------------------------------------------------------------- CSR build, pass D
// 1024 threads/block (was 256): per-edge loops drop to ~4 iterations. The
// 256-wide scan phase is guarded to t<256 with uniform barriers.
__global__ void bucket_csr(const int* __restrict__ pairs,
                           const int* __restrict__ boff,
                           const int* __restrict__ bcursor,
                           int* __restrict__ row_start,
                           int* __restrict__ adj) {
    __shared__ int cnt[256];
    __shared__ int sc[256];
    int b = blockIdx.x;
    int node0 = b << 8;
    int p0 = boff[b];
    int p1 = bcursor[b];           // after pass C, bcursor[b] = end of bucket b
    int t = threadIdx.x;
    if (t < 256) cnt[t] = 0;
    __syncthreads();
    for (int p = p0 + t; p < p1; p += 1024)
        atomicAdd(&cnt[pairs[p] & 255], 1);
    __syncthreads();
    int v = (t < 256) ? cnt[t] : 0;
    if (t < 256) sc[t] = v;
    __syncthreads();
    for (int off = 1; off < 256; off <<= 1) {
        int u = (t >= off && t < 256) ? sc[t - off] : 0;
        __syncthreads();
        if (t < 256) sc[t] += u;
        __syncthreads();
    }
    if (t < 256) {
        sc[t] = p0 + sc[t] - v;    // exclusive scan + bucket base = row_start
        int node = node0 + t;
        if (node <= N_NODES) row_start[node] = sc[t];
    }
    __syncthreads();               // row_start written before atomics mutate sc
    for (int p = p0 + t; p < p1; p += 1024) {
        int pr = pairs[p];
        int slot = atomicAdd(&sc[pr & 255], 1);
        adj[slot] = (int)(((unsigned)pr) >> 8);
    }
}

// ---------------------------------------------------------------- aggregation
// (R4 form, part of the measured 279us baseline.)
// 8 rows per wave x 8 lanes per row, uint4 (16B) gathers: 8 loads in flight
// = 128B/lane. Lane c owns features 8c..8c+7; the 8 consecutive rows of a
// wave write 1KB contiguous. No shuffle reduction.
__global__ void agg_kernel(const int* __restrict__ row_start,
                           const int* __restrict__ adj,
                           const unsigned short* __restrict__ xh,
                           unsigned short* __restrict__ M) {
    int lane = threadIdx.x & 63;
    int g = lane >> 3;                  // row group 0..7
    int c = lane & 7;                   // uint4 column (features 8c..8c+7)
    int wpb = blockDim.x >> 6;
    int wid = blockIdx.x * wpb + (threadIdx.x >> 6);
    int stride = gridDim.x * wpb;
    const uint4* xw = (const uint4*)xh;   // row stride = 8 uint4
    uint4* Mw = (uint4*)M;
    const int NQ = N_NODES / 8;           // 12500, exact
    for (int q = wid; q < NQ; q += stride) {
        int row = q * 8 + g;
        int beg = row_start[row], end = row_start[row + 1];
        float a0 = 0.f, a1 = 0.f, a2 = 0.f, a3 = 0.f;
        float a4 = 0.f, a5 = 0.f, a6 = 0.f, a7 = 0.f;
        int j = beg;
        for (; j + 7 < end; j += 8) {     // 8 uint4 gathers in flight
            int s0 = adj[j],     s1 = adj[j + 1], s2 = adj[j + 2], s3 = adj[j + 3];
            int s4 = adj[j + 4], s5 = adj[j + 5], s6 = adj[j + 6], s7 = adj[j + 7];
            uint4 v0 = xw[(size_t)s0 * 8 + c];
            uint4 v1 = xw[(size_t)s1 * 8 + c];
            uint4 v2 = xw[(size_t)s2 * 8 + c];
            uint4 v3 = xw[(size_t)s3 * 8 + c];
            uint4 v4 = xw[(size_t)s4 * 8 + c];
            uint4 v5 = xw[(size_t)s5 * 8 + c];
            uint4 v6 = xw[(size_t)s6 * 8 + c];
            uint4 v7 = xw[(size_t)s7 * 8 + c];
            a0 += bflo(v0.x) + bflo(v1.x) + bflo(v2.x) + bflo(v3.x)
                + bflo(v4.x) + bflo(v5.x) + bflo(v6.x) + bflo(v7.x);
            a1 += bfhi(v0.x) + bfhi(v1.x) + bfhi(v2.x) + bfhi(v3.x)
                + bfhi(v4.x) + bfhi(v5.x) + bfhi(v6.x) + bfhi(v7.x);
            a2 += bflo(v0.y) + bflo(v1.y) + bflo(v2.y) + bflo(v3.y)
                + bflo(v4.y) + bflo(v5.y) + bflo(v6.y) + bflo(v7.y);
            a3 += bfhi(v0.y) + bfhi(v1.y) + bfhi(v2.y) + bfhi(v3.y)
                + bfhi(v4.y) + bfhi(v5.y) + bfhi(v6.y) + bfhi(v7.y);
            a4 += bflo(v0.z) + bflo(v1.z) + bflo(v2.z) + bflo(v3.z)
                + bflo(v4.z) + bflo(v5.z) + bflo(v6.z) + bflo(v7.z);
            a5 += bfhi(v0.z) + bfhi(v1.z) + bfhi(v2.z) + bfhi(v3.z)
                + bfhi(v4.z) + bfhi(v5.z) + bfhi(v6.z) + bfhi(v7.z);
            a6 += bflo(v0.w) + bflo(v1.w) + bflo(v2.w) + bflo(v3.w)
                + bflo(v4.w) + bflo(v5.w) + bflo(v6.w) + bflo(v7.w);
            a7 += bfhi(v0.w) + bfhi(v1.w) + bfhi(v2.w) + bfhi(v3.w)
                + bfhi(v4.w) + bfhi(v5.w) + bfhi(v6.w) + bfhi(v7.w);
        }
        if (j + 3 < end) {                // 4 in flight
            int s0 = adj[j], s1 = adj[j + 1], s2 = adj[j + 2], s3 = adj[j + 3];
            uint4 v0 = xw[(size_t)s0 * 8 + c];
            uint4 v1 = xw[(size_t)s1 * 8 + c];
            uint4 v2 = xw[(size_t)s2 * 8 + c];
            uint4 v3 = xw[(size_t)s3 * 8 + c];
            a0 += bflo(v0.x) + bflo(v1.x) + bflo(v2.x) + bflo(v3.x);
            a1 += bfhi(v0.x) + bfhi(v1.x) + bfhi(v2.x) + bfhi(v3.x);
            a2 += bflo(v0.y) + bflo(v1.y) + bflo(v2.y) + bflo(v3.y);
            a3 += bfhi(v0.y) + bfhi(v1.y) + bfhi(v2.y) + bfhi(v3.y);
            a4 += bflo(v0.z) + bflo(v1.z) + bflo(v2.z) + bflo(v3.z);
            a5 += bfhi(v0.z) + bfhi(v1.z) + bfhi(v2.z) + bfhi(v3.z);
            a6 += bflo(v0.w) + bflo(v1.w) + bflo(v2.w) + bflo(v3.w);
            a7 += bfhi(v0.w) + bfhi(v1.w) + bfhi(v2.w) + bfhi(v3.w);
            j += 4;
        }
        for (; j < end; ++j) {
            uint4 v = xw[(size_t)adj[j] * 8 + c];
            a0 += bflo(v.x); a1 += bfhi(v.x);
            a2 += bflo(v.y); a3 += bfhi(v.y);
            a4 += bflo(v.z); a5 += bfhi(v.z);
            a6 += bflo(v.w); a7 += bfhi(v.w);
        }
        float inv = 1.0f / fmaxf((float)(end - beg), 1.0f);
        uint4 p;
        p.x = (unsigned)f2bf(a0 * inv) | ((unsigned)f2bf(a1 * inv) << 16);
        p.y = (unsigned)f2bf(a2 * inv) | ((unsigned)f2bf(a3 * inv) << 16);
        p.z = (unsigned)f2bf(a4 * inv) | ((unsigned)f2bf(a5 * inv) << 16);
        p.w = (unsigned)f2bf(a6 * inv) | ((unsigned)f2bf(a7 * inv) << 16);
        Mw[(size_t)row * 8 + c] = p;      // 8 rows/wave -> 1KB contiguous
    }
}

// ---------------------------------------------------------------- MFMA GEMM
__global__ void gemm_kernel(const unsigned short* __restrict__ Am,
                            const unsigned short* __restrict__ As,
                            const float* __restrict__ Wl,
                            const float* __restrict__ Wr,
                            const float* __restrict__ bias,
                            unsigned short* __restrict__ H,
                            int relu) {
    int lane = threadIdx.x & 63;
    int m = lane & 15, quad = lane >> 4;

    bf16x8 wf[2][2][4];   // [matrix][kstep][ctile]
    for (int mat = 0; mat < 2; ++mat) {
        const float* W = mat ? Wr : Wl;
        for (int ks = 0; ks < 2; ++ks)
            for (int ct = 0; ct < 4; ++ct) {
                const float* p = W + (ct * 16 + m) * HID + ks * 32 + quad * 8;
                bf16x8 f;
                #pragma unroll
                for (int j = 0; j < 8; ++j) f[j] = (short)f2bf(p[j]);
                wf[mat][ks][ct] = f;
            }
    }
    float bv[4];
    #pragma unroll
    for (int ct = 0; ct < 4; ++ct) bv[ct] = bias[ct * 16 + m];

    int wpb = blockDim.x >> 6;
    int wid = blockIdx.x * wpb + (threadIdx.x >> 6);
    int stride = gridDim.x * wpb;
    const int NT = N_NODES / 16;
    for (int t = wid; t < NT; t += stride) {
        f32x4 acc[4] = {{0,0,0,0},{0,0,0,0},{0,0,0,0},{0,0,0,0}};
        size_t rowbase = ((size_t)t * 16 + m) * HID;
        #pragma unroll
        for (int ks = 0; ks < 2; ++ks) {
            bf16x8 a0 = *(const bf16x8*)(Am + rowbase + ks * 32 + quad * 8);
            bf16x8 a1 = *(const bf16x8*)(As + rowbase + ks * 32 + quad * 8);
            #pragma unroll
            for (int ct = 0; ct < 4; ++ct) {
                acc[ct] = __builtin_amdgcn_mfma_f32_16x16x32_bf16(a0, wf[0][ks][ct], acc[ct], 0, 0, 0);
                acc[ct] = __builtin_amdgcn_mfma_f32_16x16x32_bf16(a1, wf[1][ks][ct], acc[ct], 0, 0, 0);
            }
        }
        #pragma unroll
        for (int ct = 0; ct < 4; ++ct) {
            #pragma unroll
            for (int r = 0; r < 4; ++r) {
                float v = acc[ct][r] + bv[ct];
                if (relu) v = fmaxf(v, 0.f);
                H[((size_t)t * 16 + quad * 4 + r) * HID + ct * 16 + m] = f2bf(v);
            }
        }
    }
}

// ---------------------------------------------------------------- edge dot (bf16)
// Flat edge-order form (measured 43.1us at the 3.64 TB/s fetch-path ceiling):
// 8 lanes per 2 consecutive edges, 4 uint4 gathers in flight/lane,
// coalesced float2 output write. No per-row loop -> MLP never collapses.
__global__ void edge_dot_kernel(const int* __restrict__ src,
                                const int* __restrict__ dst,
                                const unsigned short* __restrict__ h,
                                float* __restrict__ out) {
    int t = blockIdx.x * blockDim.x + threadIdx.x;
    int g = t >> 3;                 // edge-pair group
    int c = t & 7;
    int e0 = g * 2;
    if (e0 >= N_EDGES) return;
    int a0 = src[e0],     b0 = dst[e0];
    int a1 = src[e0 + 1], b1 = dst[e0 + 1];
    const uint4* h4 = reinterpret_cast<const uint4*>(h);
    uint4 va0 = h4[(size_t)a0 * 8 + c];
    uint4 vb0 = h4[(size_t)b0 * 8 + c];
    uint4 va1 = h4[(size_t)a1 * 8 + c];
    uint4 vb1 = h4[(size_t)b1 * 8 + c];
    float p0 = bflo(va0.x) * bflo(vb0.x) + bfhi(va0.x) * bfhi(vb0.x)
             + bflo(va0.y) * bflo(vb0.y) + bfhi(va0.y) * bfhi(vb0.y)
             + bflo(va0.z) * bflo(vb0.z) + bfhi(va0.z) * bfhi(vb0.z)
             + bflo(va0.w) * bflo(vb0.w) + bfhi(va0.w) * bfhi(vb0.w);
    float p1 = bflo(va1.x) * bflo(vb1.x) + bfhi(va1.x) * bfhi(vb1.x)
             + bflo(va1.y) * bflo(vb1.y) + bfhi(va1.y) * bfhi(vb1.y)
             + bflo(va1.z) * bflo(vb1.z) + bfhi(va1.z) * bfhi(vb1.z)
             + bflo(va1.w) * bflo(vb1.w) + bfhi(va1.w) * bfhi(vb1.w);
    p0 += __shfl_xor(p0, 1); p0 += __shfl_xor(p0, 2); p0 += __shfl_xor(p0, 4);
    p1 += __shfl_xor(p1, 1); p1 += __shfl_xor(p1, 2); p1 += __shfl_xor(p1, 4);
    if (c == 0) reinterpret_cast<float2*>(out)[g] = make_float2(p0, p1);
}

extern "C" void kernel_launch(void* const* d_in, const int* in_sizes, int n_in,
                              void* d_out, int out_size, void* d_ws, size_t ws_size,
                              hipStream_t stream) {
    const float* emb = (const float*)d_in[0];
    const float* Wl1 = (const float*)d_in[1];
    const float* Wr1 = (const float*)d_in[2];
    const float* b1  = (const float*)d_in[3];
    const float* Wl2 = (const float*)d_in[4];
    const float* Wr2 = (const float*)d_in[5];
    const float* b2  = (const float*)d_in[6];
    const int*   nid = (const int*)d_in[7];
    const int*   ei  = (const int*)d_in[8];
    const int* esrc = ei;
    const int* edst = ei + N_EDGES;
    float* out = (float*)d_out;

    const size_t NH = (size_t)N_NODES * HID;   // 6.4M elements
    unsigned short* xh  = (unsigned short*)d_ws;          // [N,64] bf16
    unsigned short* h1h = xh + NH;                        // [N,64] bf16
    unsigned short* h2h = h1h + NH;                       // [N,64] bf16
    unsigned short* M   = h2h + NH;                       // [N,64] bf16 (mean agg)
    int* ib        = (int*)(M + NH);                      // int region
    int* row_start = ib;                          // [N+1]
    int* adj       = ib + N_NODES + 64;           // [E]
    int* pairs     = adj + N_EDGES + 64;          // [E] packed (src<<8)|(dst&255)
    int* bhist_part = pairs + N_EDGES;            // [NHB*NBP] chunk hists
    int* boff      = bhist_part + NHB * NBP;      // [NB]
    int* bcursor   = boff + NB + 1;               // [NB]

    // fused: xh = bf16(emb[node_id])  +  per-chunk dst-bucket histograms
    gather_hist_kernel<<<GATHER_BLOCKS + NHB, 256, 0, stream>>>(emb, nid, xh, edst, bhist_part);

    // ---- CSR build via bucket counting sort (shared by both layers)
    bucket_scan<<<1, 512, 0, stream>>>(bhist_part, boff, bcursor);
    bucket_scatter<<<NHB, 1024, 0, stream>>>(esrc, edst, bhist_part, bcursor, pairs);
    bucket_csr<<<NB, 1024, 0, stream>>>(pairs, boff, bcursor, row_start, adj);

    // ---- layer 1: aggregate then MFMA GEMM (+relu)
    agg_kernel<<<2048, 256, 0, stream>>>(row_start, adj, xh, M);
    gemm_kernel<<<512, 256, 0, stream>>>(M, xh, Wl1, Wr1, b1, h1h, 1);

    // ---- layer 2
    agg_kernel<<<2048, 256, 0, stream>>>(row_start, adj, h1h, M);
    gemm_kernel<<<512, 256, 0, stream>>>(M, h1h, Wl2, Wr2, b2, h2h, 0);

    // ---- edge classifier on bf16 features (flat edge-order, at path ceiling)
    edge_dot_kernel<<<((size_t)(N_EDGES / 2) * 8 + 255) / 256, 256, 0, stream>>>(esrc, edst, h2h, out);
}